// Round 4
// baseline (61230.316 us; speedup 1.0000x reference)
//
#include <hip/hip_runtime.h>

namespace {

constexpr int B = 128;
constexpr int T = 1024;
constexpr int DIN = 48;
constexpr int H = 256;
constexpr int G = 4 * H;          // 1024 gate rows per direction
constexpr int NTHREADS = 512;

constexpr size_t BH           = (size_t)B * H;                       // 32768
constexpr size_t WT_FLOATS    = 4 * 256 * 1024 + 2 * 48 * 1024 + 2 * 512 * 1024; // 2,195,456
constexpr size_t STATE_FLOATS = 12 * BH;                             // 393,216
constexpr size_t FLAG_INTS    = 1024;                                // 33 counters, 64B-strided, padded
constexpr size_t O0_ELEMS     = (size_t)B * T * 512;                 // 67,108,864

__device__ __forceinline__ float sigmoidf_(float x) {
    float z = __expf(-fabsf(x));
    float s = 1.0f / (1.0f + z);
    return x >= 0.0f ? s : 1.0f - s;
}
__device__ __forceinline__ float tanhf_(float x) {
    float z = __expf(-2.0f * fabsf(x));
    float tp = (1.0f - z) / (1.0f + z);
    return x >= 0.0f ? tp : -tp;
}
__device__ __forceinline__ float bf2f(unsigned short s) {
    union { unsigned int u; float f; } v; v.u = ((unsigned int)s) << 16; return v.f;
}
__device__ __forceinline__ unsigned short f2bf(float f) {
    union { float f; unsigned int u; } v; v.f = f;
    unsigned int u = v.u;
    return (unsigned short)((u + 0x7FFFu + ((u >> 16) & 1u)) >> 16);  // RNE
}

__global__ void zero_f(float* __restrict__ p, int n) {
    int i = blockIdx.x * blockDim.x + threadIdx.x;
    if (i < n) p[i] = 0.0f;
}

// dst[k][r] = src[r][k], src is [1024][K]; output-coalesced
__global__ void transpose_w(const float* __restrict__ src, float* __restrict__ dst, int K) {
    int idx = blockIdx.x * blockDim.x + threadIdx.x;
    if (idx >= K * 1024) return;
    int r = idx & 1023;
    int k = idx >> 10;
    dst[idx] = src[r * K + k];
}

// One recurrence step for one block (dir d, 8-batch tile b0, 32-channel tile c0).
// Identical math to the passing per-launch kernel; adds (a) x-staging hoisted
// before the group spin-wait (latency overlap), (b) agent-scope h loads/stores
// (cross-XCD visibility without L2-flushing fences), (c) h_old read from LDS.
template<int INP, int XKK, int XSL, int XPB, int KSMAX, bool WRITE_OUT, typename XT, typename OT>
__device__ __forceinline__ void step_body(
    int t, int dsel, int b0, int c0,
    const XT* __restrict__ xin, int xstride,
    const float* __restrict__ wih_t, const float* __restrict__ whh_t,
    const float* __restrict__ bih,  const float* __restrict__ bhh,
    const float* __restrict__ hrow_in, float* __restrict__ hrow_out,
    float* __restrict__ crow, OT* __restrict__ oout,
    const int* __restrict__ lengths,
    float4* lds_x4, float4* lds_h4, float* lds_g,
    int* flag_ptr, int wait_target)
{
    const int tid = threadIdx.x;
    const int ks  = tid & 15;               // k-slice
    const int rq  = tid >> 4;               // row-quad 0..31

    // ---- stage x tile (issued BEFORE the wait: overlaps spin latency) ----
    {
        const int nchunk = INP / 4;
        for (int i = tid; i < 8 * nchunk; i += NTHREADS) {
            int b, k4;
            if constexpr (INP == 48) { b = i / 12; k4 = i - b * 12; }
            else                     { b = i >> 7; k4 = i & 127; }
            const XT* src = xin + ((size_t)(b0 + b) * T + t) * xstride + k4 * 4;
            float4 v;
            if constexpr (sizeof(XT) == 4) {
                v = *(const float4*)src;
            } else {
                ushort4 uv = *(const ushort4*)src;
                v = make_float4(bf2f(uv.x), bf2f(uv.y), bf2f(uv.z), bf2f(uv.w));
            }
            int slot;
            if constexpr (INP == 48) slot = b * XPB + k4 * XSL;                      // XKK=1: k4==ks
            else                     slot = b * XPB + (k4 >> 3) * XSL + (k4 & 7);    // XKK=8
            lds_x4[slot] = v;
        }
    }

    // ---- wait until all 8 group peers have published h for step t-1 ----
    if (wait_target > 0) {
        if (tid == 0) {
            while (__hip_atomic_load(flag_ptr, __ATOMIC_RELAXED, __HIP_MEMORY_SCOPE_AGENT) < wait_target)
                __builtin_amdgcn_s_sleep(1);
        }
        __syncthreads();
    }

    // ---- stage h tile (agent-scope scalar loads -> coherent point) ----
    for (int i = tid; i < 8 * 256; i += NTHREADS) {
        int b = i >> 8, k = i & 255;
        float v = __hip_atomic_load(hrow_in + (b0 + b) * H + k,
                                    __ATOMIC_RELAXED, __HIP_MEMORY_SCOPE_AGENT);
        ((float*)lds_h4)[(b * 80 + (k >> 4) * 5 + ((k >> 2) & 3)) * 4 + (k & 3)] = v;
    }
    __syncthreads();

    const int rbase = rq * 4;               // local row 0..124 (gate-major: 4 gates x 32 ch)
    const int gate  = rbase >> 5;
    const int chl4  = rbase & 31;
    const int grow0 = gate * 256 + c0 + chl4;   // global gate-row of acc[0] (4-aligned)

    float acc[4][8];
    #pragma unroll
    for (int i = 0; i < 4; i++)
        #pragma unroll
        for (int b = 0; b < 8; b++) acc[i][b] = 0.0f;

    // ---- x part ----
    if (ks < KSMAX) {
        #pragma unroll
        for (int kk = 0; kk < XKK; kk++) {
            float4 xv[8];
            #pragma unroll
            for (int b = 0; b < 8; b++) xv[b] = lds_x4[b * XPB + ks * XSL + kk];
            const int kbase = (ks * XKK + kk) * 4;
            #pragma unroll
            for (int j = 0; j < 4; j++) {
                float4 w4 = *(const float4*)(wih_t + (kbase + j) * G + grow0);
                #pragma unroll
                for (int b = 0; b < 8; b++) {
                    float xs = (j == 0) ? xv[b].x : (j == 1) ? xv[b].y : (j == 2) ? xv[b].z : xv[b].w;
                    acc[0][b] = fmaf(w4.x, xs, acc[0][b]);
                    acc[1][b] = fmaf(w4.y, xs, acc[1][b]);
                    acc[2][b] = fmaf(w4.z, xs, acc[2][b]);
                    acc[3][b] = fmaf(w4.w, xs, acc[3][b]);
                }
            }
        }
    }

    // ---- h part: K=256, 16 floats per ks ----
    #pragma unroll
    for (int kk = 0; kk < 4; kk++) {
        float4 hv[8];
        #pragma unroll
        for (int b = 0; b < 8; b++) hv[b] = lds_h4[b * 80 + ks * 5 + kk];
        const int kbase = (ks * 4 + kk) * 4;
        #pragma unroll
        for (int j = 0; j < 4; j++) {
            float4 w4 = *(const float4*)(whh_t + (kbase + j) * G + grow0);
            #pragma unroll
            for (int b = 0; b < 8; b++) {
                float xs = (j == 0) ? hv[b].x : (j == 1) ? hv[b].y : (j == 2) ? hv[b].z : hv[b].w;
                acc[0][b] = fmaf(w4.x, xs, acc[0][b]);
                acc[1][b] = fmaf(w4.y, xs, acc[1][b]);
                acc[2][b] = fmaf(w4.z, xs, acc[2][b]);
                acc[3][b] = fmaf(w4.w, xs, acc[3][b]);
            }
        }
    }

    // ---- reduce over the 16 k-slices (lane bits 0..3) ----
    #pragma unroll
    for (int i = 0; i < 4; i++)
        #pragma unroll
        for (int b = 0; b < 8; b++) {
            float v = acc[i][b];
            v += __shfl_xor(v, 1, 64);
            v += __shfl_xor(v, 2, 64);
            v += __shfl_xor(v, 4, 64);
            v += __shfl_xor(v, 8, 64);
            acc[i][b] = v;
        }
    if (ks == 0) {
        #pragma unroll
        for (int i = 0; i < 4; i++)
            #pragma unroll
            for (int b = 0; b < 8; b++)
                lds_g[(rbase + i) * 9 + b] = acc[i][b];
    }
    __syncthreads();

    // ---- elementwise gate math: 256 (channel, batch) pairs ----
    if (tid < 256) {
        const int chl = tid & 31;
        const int b   = tid >> 5;
        const int gch = c0 + chl;
        float gi = lds_g[(0 * 32 + chl) * 9 + b] + bih[0 * 256 + gch] + bhh[0 * 256 + gch];
        float gf = lds_g[(1 * 32 + chl) * 9 + b] + bih[1 * 256 + gch] + bhh[1 * 256 + gch];
        float gg = lds_g[(2 * 32 + chl) * 9 + b] + bih[2 * 256 + gch] + bhh[2 * 256 + gch];
        float go = lds_g[(3 * 32 + chl) * 9 + b] + bih[3 * 256 + gch] + bhh[3 * 256 + gch];
        float iv = sigmoidf_(gi);
        float fv = sigmoidf_(gf);
        float gv = tanhf_(gg);
        float ov = sigmoidf_(go);
        const int sidx = (b0 + b) * H + gch;
        float c_old = crow[sidx];                     // block-private: plain ld/st
        float h_old = ((float*)lds_h4)[(b * 80 + (gch >> 4) * 5 + ((gch >> 2) & 3)) * 4 + (gch & 3)];
        float c_new = fv * c_old + iv * gv;
        float h_new = ov * tanhf_(c_new);
        bool valid = t < lengths[b0 + b];
        if (valid) crow[sidx] = c_new;
        __hip_atomic_store(hrow_out + sidx, valid ? h_new : h_old,
                           __ATOMIC_RELAXED, __HIP_MEMORY_SCOPE_AGENT);
        if constexpr (WRITE_OUT) {
            float hv = valid ? h_new : 0.0f;
            size_t oidx = ((size_t)(b0 + b) * T + t) * 512 + dsel * 256 + gch;
            if constexpr (sizeof(OT) == 4)
                __hip_atomic_store(oout + oidx, hv, __ATOMIC_RELAXED, __HIP_MEMORY_SCOPE_AGENT);
            else
                __hip_atomic_store(oout + oidx, f2bf(hv), __ATOMIC_RELAXED, __HIP_MEMORY_SCOPE_AGENT);
        }
    }
}

// Persistent kernel: whole 2x1024-step recurrence in one dispatch.
// 256 blocks (= CU count -> co-resident). Sync: 32 independent 8-member group
// counters (one per (dir, batch-tile)); one grid-wide barrier between layers.
template<typename OT>
__global__ __launch_bounds__(NTHREADS)
void lstm_persist(const float* __restrict__ x,
    const float* __restrict__ wih0f, const float* __restrict__ wih0b,
    const float* __restrict__ whh0f, const float* __restrict__ whh0b,
    const float* __restrict__ bih0f, const float* __restrict__ bhh0f,
    const float* __restrict__ bih0b, const float* __restrict__ bhh0b,
    const float* __restrict__ wih1f, const float* __restrict__ wih1b,
    const float* __restrict__ whh1f, const float* __restrict__ whh1b,
    const float* __restrict__ bih1f, const float* __restrict__ bhh1f,
    const float* __restrict__ bih1b, const float* __restrict__ bhh1b,
    float* __restrict__ h_l0, float* __restrict__ h_l1,
    float* __restrict__ c_l0, float* __restrict__ c_l1,
    OT* __restrict__ O0, const int* __restrict__ lengths, int* __restrict__ flags)
{
    const int bx  = blockIdx.x;
    const int d   = bx >> 7;                // 0 fwd, 1 bwd
    const int rem = bx & 127;
    const int b0  = (rem >> 3) * 8;
    const int c0  = (rem & 7) * 32;         // ctile = bx&7 -> per-XCD weight locality
    const int tid = threadIdx.x;
    const int g   = d * 16 + (rem >> 3);    // sync group: (dir, batch-tile), 8 members
    int* flag_ptr = &flags[g * 16];

    __shared__ float4 lds_x4[8 * 144];
    __shared__ float4 lds_h4[8 * 80];
    __shared__ float  lds_g[128 * 9];

    // ================= phase 0: layer 0 =================
    {
        const float* wih_t = d ? wih0b : wih0f;
        const float* whh_t = d ? whh0b : whh0f;
        const float* bih   = d ? bih0b : bih0f;
        const float* bhh   = d ? bhh0b : bhh0f;
        float* crow = c_l0 + d * (B * H);
        for (int s = 0; s < T; ++s) {
            const int t = d ? (T - 1 - s) : s;
            const float* hin = h_l0 + ((size_t)((s & 1) * 2 + d)) * (B * H);
            float*       hout= h_l0 + ((size_t)(((s & 1) ^ 1) * 2 + d)) * (B * H);
            step_body<48, 1, 3, 48, 12, true, float, OT>(
                t, d, b0, c0, x, DIN, wih_t, whh_t, bih, bhh,
                hin, hout, crow, O0, lengths, lds_x4, lds_h4, lds_g,
                flag_ptr, 8 * s);
            __syncthreads();   // all h stores drained (vmcnt) before publishing
            if (tid == 0)
                __hip_atomic_fetch_add(flag_ptr, 1, __ATOMIC_RELAXED, __HIP_MEMORY_SCOPE_AGENT);
        }
    }

    // ================= grid-wide phase barrier =================
    __syncthreads();
    if (tid == 0) {
        __threadfence();
        __hip_atomic_fetch_add(&flags[32 * 16], 1, __ATOMIC_ACQ_REL, __HIP_MEMORY_SCOPE_AGENT);
        while (__hip_atomic_load(&flags[32 * 16], __ATOMIC_ACQUIRE, __HIP_MEMORY_SCOPE_AGENT) < 256)
            __builtin_amdgcn_s_sleep(2);
        __threadfence();
    }
    __syncthreads();

    // ================= phase 1: layer 1 =================
    {
        const float* wih_t = d ? wih1b : wih1f;
        const float* whh_t = d ? whh1b : whh1f;
        const float* bih   = d ? bih1b : bih1f;
        const float* bhh   = d ? bhh1b : bhh1f;
        float* crow = c_l1 + d * (B * H);
        for (int s = 0; s < T; ++s) {
            const int t = d ? (T - 1 - s) : s;
            const float* hin = h_l1 + ((size_t)((s & 1) * 2 + d)) * (B * H);
            float*       hout= h_l1 + ((size_t)(((s & 1) ^ 1) * 2 + d)) * (B * H);
            step_body<512, 8, 9, 144, 16, false, OT, OT>(
                t, d, b0, c0, O0, 512, wih_t, whh_t, bih, bhh,
                hin, hout, crow, (OT*)nullptr, lengths, lds_x4, lds_h4, lds_g,
                flag_ptr, 8 * (T + s));
            __syncthreads();
            if (tid == 0)
                __hip_atomic_fetch_add(flag_ptr, 1, __ATOMIC_RELAXED, __HIP_MEMORY_SCOPE_AGENT);
        }
    }
}

__global__ __launch_bounds__(256)
void fc_head(const float* __restrict__ h1,   // [2][B][H] final layer-1 h (parity 0)
             const float* __restrict__ fc1w, const float* __restrict__ fc1b,
             const float* __restrict__ fc2w, const float* __restrict__ fc2b,
             float* __restrict__ out)
{
    int b = blockIdx.x;
    int tid = threadIdx.x;
    __shared__ float hid[512];
    __shared__ float red[4];
    hid[tid]       = h1[b * H + tid];
    hid[256 + tid] = h1[(size_t)B * H + b * H + tid];
    __syncthreads();
    float a = fc1b[tid];
    const float4* w4 = (const float4*)(fc1w + tid * 512);
    const float4* h4 = (const float4*)hid;
    #pragma unroll 4
    for (int k = 0; k < 128; k++) {
        float4 w = w4[k], h = h4[k];
        a = fmaf(w.x, h.x, a); a = fmaf(w.y, h.y, a);
        a = fmaf(w.z, h.z, a); a = fmaf(w.w, h.w, a);
    }
    float r = fmaxf(a, 0.0f);
    float v = r * fc2w[tid];
    #pragma unroll
    for (int off = 32; off > 0; off >>= 1) v += __shfl_down(v, off, 64);
    if ((tid & 63) == 0) red[tid >> 6] = v;
    __syncthreads();
    if (tid == 0) out[b] = red[0] + red[1] + red[2] + red[3] + fc2b[0];
}

} // namespace

extern "C" void kernel_launch(void* const* d_in, const int* in_sizes, int n_in,
                              void* d_out, int out_size, void* d_ws, size_t ws_size,
                              hipStream_t stream)
{
    const float* x        = (const float*)d_in[0];
    const int*   lengths  = (const int*)d_in[1];
    const float* w_ih_l0f = (const float*)d_in[2];
    const float* w_hh_l0f = (const float*)d_in[3];
    const float* b_ih_l0f = (const float*)d_in[4];
    const float* b_hh_l0f = (const float*)d_in[5];
    const float* w_ih_l0b = (const float*)d_in[6];
    const float* w_hh_l0b = (const float*)d_in[7];
    const float* b_ih_l0b = (const float*)d_in[8];
    const float* b_hh_l0b = (const float*)d_in[9];
    const float* w_ih_l1f = (const float*)d_in[10];
    const float* w_hh_l1f = (const float*)d_in[11];
    const float* b_ih_l1f = (const float*)d_in[12];
    const float* b_hh_l1f = (const float*)d_in[13];
    const float* w_ih_l1b = (const float*)d_in[14];
    const float* w_hh_l1b = (const float*)d_in[15];
    const float* b_ih_l1b = (const float*)d_in[16];
    const float* b_hh_l1b = (const float*)d_in[17];
    const float* fc1w     = (const float*)d_in[18];
    const float* fc1b     = (const float*)d_in[19];
    const float* fc2w     = (const float*)d_in[20];
    const float* fc2b     = (const float*)d_in[21];

    float* ws = (float*)d_ws;

    // ---- workspace layout: [weights | state | flags | O0] ----
    float* whh_t_l0f = ws;
    float* whh_t_l0b = whh_t_l0f + 256 * 1024;
    float* whh_t_l1f = whh_t_l0b + 256 * 1024;
    float* whh_t_l1b = whh_t_l1f + 256 * 1024;
    float* wih_t_l0f = whh_t_l1b + 256 * 1024;  // [48][1024]
    float* wih_t_l0b = wih_t_l0f + 48 * 1024;
    float* wih_t_l1f = wih_t_l0b + 48 * 1024;   // [512][1024]
    float* wih_t_l1b = wih_t_l1f + 512 * 1024;

    float* state = ws + WT_FLOATS;
    float* h_l0 = state;                        // [2 parity][2 dir][B][H]
    float* h_l1 = h_l0 + 4 * BH;
    float* c_l0 = h_l1 + 4 * BH;                // [2 dir][B][H]
    float* c_l1 = c_l0 + 2 * BH;
    int*   flags = (int*)(state + STATE_FLOATS);
    void*  O0   = (void*)(state + STATE_FLOATS + FLAG_INTS);

    // ws_size is invariant across calls -> deterministic branch.
    const size_t base_bytes = (WT_FLOATS + STATE_FLOATS + FLAG_INTS) * sizeof(float);
    const bool o0_f32 = ws_size >= base_bytes + O0_ELEMS * sizeof(float);

    // zero h/c state AND sync flags (ws is poisoned 0xAA before every call)
    zero_f<<<(int)((STATE_FLOATS + FLAG_INTS + 255) / 256), 256, 0, stream>>>(
        state, (int)(STATE_FLOATS + FLAG_INTS));

    // weight transposes (per call; cheap, graph-captured)
    transpose_w<<<256 * 1024 / 256, 256, 0, stream>>>(w_hh_l0f, whh_t_l0f, 256);
    transpose_w<<<256 * 1024 / 256, 256, 0, stream>>>(w_hh_l0b, whh_t_l0b, 256);
    transpose_w<<<256 * 1024 / 256, 256, 0, stream>>>(w_hh_l1f, whh_t_l1f, 256);
    transpose_w<<<256 * 1024 / 256, 256, 0, stream>>>(w_hh_l1b, whh_t_l1b, 256);
    transpose_w<<<48 * 1024 / 256, 256, 0, stream>>>(w_ih_l0f, wih_t_l0f, 48);
    transpose_w<<<48 * 1024 / 256, 256, 0, stream>>>(w_ih_l0b, wih_t_l0b, 48);
    transpose_w<<<512 * 1024 / 256, 256, 0, stream>>>(w_ih_l1f, wih_t_l1f, 512);
    transpose_w<<<512 * 1024 / 256, 256, 0, stream>>>(w_ih_l1b, wih_t_l1b, 512);

    if (o0_f32) {
        lstm_persist<float><<<256, NTHREADS, 0, stream>>>(
            x,
            wih_t_l0f, wih_t_l0b, whh_t_l0f, whh_t_l0b,
            b_ih_l0f, b_hh_l0f, b_ih_l0b, b_hh_l0b,
            wih_t_l1f, wih_t_l1b, whh_t_l1f, whh_t_l1b,
            b_ih_l1f, b_hh_l1f, b_ih_l1b, b_hh_l1b,
            h_l0, h_l1, c_l0, c_l1,
            (float*)O0, lengths, flags);
    } else {
        lstm_persist<unsigned short><<<256, NTHREADS, 0, stream>>>(
            x,
            wih_t_l0f, wih_t_l0b, whh_t_l0f, whh_t_l0b,
            b_ih_l0f, b_hh_l0f, b_ih_l0b, b_hh_l0b,
            wih_t_l1f, wih_t_l1b, whh_t_l1f, whh_t_l1b,
            b_ih_l1f, b_hh_l1f, b_ih_l1b, b_hh_l1b,
            h_l0, h_l1, c_l0, c_l1,
            (unsigned short*)O0, lengths, flags);
    }
    // FC head: T even -> final h lives at parity 0
    fc_head<<<B, 256, 0, stream>>>(h_l1, fc1w, fc1b, fc2w, fc2b, (float*)d_out);
}